// Round 16
// baseline (37.088 us; speedup 1.0000x reference)
//
#include <hip/hip_runtime.h>

// ---------------------------------------------------------------------------
// out = w .* mc + d * e0,   d = 0.5*ln(S1/S2) = 0.5*ln2*(log2 S1 - log2 S2)
// Swapped MFMA (16x16x32 f16):  D = Bmat^T * mc^T; lane's C/D regs hold 4
// spectral cols of ONE mc-row -> reduce = in-lane adds + 2 shfl_xor, after
// which ALL lanes hold S1,S2 (hence d) for their row.
// (b2mc∘mc2b == I so the 25x25 matmuls collapse; verified rounds 1-15.)
//
// R16: TWO PURE-STREAM KERNELS. Six single-kernel structures all converge
// at 24.3-24.7us with effective HBM ~3.2 TB/s (50% of the 6.7 TB/s the
// harness's own fillBuffer hits) -- the read/compute/write mixing is the
// last unfalsified limiter. k1 = R15 minus store epilogue, writes only
// d[524288] (2MB) to d_ws (read-dominated). k2 = grid-stride elementwise
// apply (mc L3-resident from k1, d L2-resident; write-dominated).
// ---------------------------------------------------------------------------

namespace cg {

constexpr int L  = 128;
constexpr int M1 = 25;

struct CosTab { double v[L]; };
constexpr CosTab make_costab() {
    CosTab t{};
    const double PI = 3.14159265358979323846;
    for (int i = 0; i < L; ++i) {
        int j = (i <= 64) ? i : i - 128;
        double x = (2.0 * PI * (double)j) / 128.0;
        double x2 = x * x, term = 1.0, s = 1.0;
        for (int n = 1; n <= 16; ++n) {
            term *= -x2 / ((2.0 * n - 1.0) * (2.0 * n));
            s += term;
        }
        t.v[i] = s;
    }
    return t;
}
constexpr CosTab CT = make_costab();

struct AMat { double v[L][M1]; };
constexpr AMat make_aft() {
    AMat A{};
    const double al = -0.42;          // freqt called with -ALPHA
    double p = 1.0;
    for (int j = 0; j < M1; ++j) { A.v[0][j] = p; p *= al; }
    double q = 1.0;
    for (int j = 1; j < M1; ++j) { A.v[1][j] = q * (double)j * (1.0 - al * al); q *= al; }
    for (int i = 2; i < L; ++i)
        for (int j = 1; j < M1; ++j)
            A.v[i][j] = A.v[i - 1][j - 1] + al * (A.v[i][j - 1] - A.v[i - 1][j]);
    return A;
}
constexpr AMat AFT = make_aft();

struct Chunk { double v[8][M1]; };
template <int K0>
constexpr Chunk make_chunk() {
    Chunk c{};
    for (int kk = 0; kk < 8; ++kk) {
        int k = K0 + kk;
        for (int m = 0; m < M1; ++m) {
            double s = 0.0;
            for (int l = 0; l < L; ++l)
                s += AFT.v[l][m] * CT.v[(k * l) & 127];
            c.v[kk][m] = s;
        }
    }
    return c;
}
constexpr Chunk CH0 = make_chunk<0>();
constexpr Chunk CH1 = make_chunk<8>();
constexpr Chunk CH2 = make_chunk<16>();
constexpr Chunk CH3 = make_chunk<24>();
constexpr Chunk CH4 = make_chunk<32>();
constexpr Chunk CH5 = make_chunk<40>();
constexpr Chunk CH6 = make_chunk<48>();
constexpr Chunk CH7 = make_chunk<56>();
constexpr Chunk CH8 = make_chunk<64>();

constexpr double chunkval(int bin, int m) {
    const Chunk* chs[9] = { &CH0, &CH1, &CH2, &CH3, &CH4, &CH5, &CH6, &CH7, &CH8 };
    return chs[bin >> 3]->v[bin & 7][m];
}

constexpr double blogical(int k, int col) {
    const double LOG2E = 1.44269504088896340736;
    if (col >= 130) return (k == 25) ? -1.0e4 : 0.0;     // pad cols: exp2 -> 0
    int bin = (col < 65) ? col : (col - 65);
    if (k == 25) return (bin == 0 || bin == 64) ? 0.0 : 1.0;  // log2(bin wt)
    if (k > 25) return 0.0;
    double c = LOG2E * 2.0 * chunkval(bin, k);
    if (col >= 65 && k >= 2) c *= 1.2;                   // cepstral weight
    return c;
}

// constexpr float->half (RN-ish; accuracy far beyond what we need)
constexpr unsigned short f2h(double v) {
    if (v == 0.0) return 0;
    unsigned short s = 0;
    if (v < 0) { s = 0x8000; v = -v; }
    int e = 0;
    while (v >= 2.0) { v *= 0.5; ++e; }
    while (v < 1.0)  { v *= 2.0; --e; }
    if (e > 15) return (unsigned short)(s | 0x7c00);
    if (e < -14) return s;                               // flush tiny to 0
    int mant = (int)((v - 1.0) * 1024.0 + 0.5);
    if (mant == 1024) { mant = 0; ++e; if (e > 15) return (unsigned short)(s | 0x7c00); }
    return (unsigned short)(s | ((e + 15) << 10) | mant);
}

// A-operand fragment per tile: lane l, reg j holds A[i=l&15][k=(l>>4)*8+j]
//   = Bmat[(l>>4)*8+j][N*16 + (l&15)]
struct Tile { unsigned short v[64][8]; };
template <int N>
constexpr Tile make_tile() {
    Tile t{};
    for (int l = 0; l < 64; ++l)
        for (int j = 0; j < 8; ++j)
            t.v[l][j] = f2h(blogical((l >> 4) * 8 + j, N * 16 + (l & 15)));
    return t;
}
constexpr Tile T0 = make_tile<0>();
constexpr Tile T1 = make_tile<1>();
constexpr Tile T2 = make_tile<2>();
constexpr Tile T3 = make_tile<3>();
constexpr Tile T4 = make_tile<4>();
constexpr Tile T5 = make_tile<5>();
constexpr Tile T6 = make_tile<6>();
constexpr Tile T7 = make_tile<7>();
constexpr Tile T8 = make_tile<8>();

struct BH { alignas(16) unsigned short v[9][64][8]; };
constexpr BH make_bh() {
    BH b{};
    const Tile* ts[9] = { &T0, &T1, &T2, &T3, &T4, &T5, &T6, &T7, &T8 };
    for (int n = 0; n < 9; ++n)
        for (int l = 0; l < 64; ++l)
            for (int j = 0; j < 8; ++j)
                b.v[n][l][j] = ts[n]->v[l][j];
    return b;
}

} // namespace cg

__device__ const cg::BH g_Bh = cg::make_bh();

typedef _Float16 f16x8 __attribute__((ext_vector_type(8)));
typedef float    f32x4 __attribute__((ext_vector_type(4)));

// ---------------------------------------------------------------------------
// k1: compute d for all rows. 4 waves/block, one 16-row group per wave.
// Read-dominated stream (26-52 MB in, 2 MB out).
// ---------------------------------------------------------------------------
__global__ __launch_bounds__(256, 4)
void mcpf_d(const float* __restrict__ mc, float* __restrict__ dbuf) {
    __shared__ __align__(16) float sbuf[4 * 408 + 8];    // 6.6 KB (+overread pad)
    const int tid  = threadIdx.x;
    const int lane = tid & 63;
    const int wv   = tid >> 6;
    const int r0   = lane & 15;
    const int kg   = lane >> 4;

    float* __restrict__ wbuf = &sbuf[wv * 408];
    const long long gw  = (long long)blockIdx.x * 4 + wv;
    const long long b4  = gw * 100;                      // float4 base (16 rows)

    const float4* __restrict__ src4 = reinterpret_cast<const float4*>(mc);

    // B-matrix fragments (rodata, L2-resident): 9x 16B loads
    f16x8 bfrag[9];
#pragma unroll
    for (int n = 0; n < 9; ++n)
        bfrag[n] = *reinterpret_cast<const f16x8*>(&g_Bh.v[n][lane][0]);

    // stage this wave's 100 float4 into its LDS buffer (linear dest)
    {
        const float4* __restrict__ s_ = src4 + b4;
        __builtin_amdgcn_global_load_lds(
            (const __attribute__((address_space(1))) float*)
                (const float*)(s_ + lane),
            (__attribute__((address_space(3))) float*)(wbuf),
            16, 0, 0);
        if (lane < 36)
            __builtin_amdgcn_global_load_lds(
                (const __attribute__((address_space(1))) float*)
                    (const float*)(s_ + lane + 64),
                (__attribute__((address_space(3))) float*)(wbuf + 256),
                16, 0, 0);
    }
    asm volatile("s_waitcnt vmcnt(0)" ::: "memory");

    const float* __restrict__ arow = &wbuf[r0 * 25 + kg * 8];

    // data fragment (B-operand): lane holds row r0, k = kg*8 + j.
    float tmp[8];
#pragma unroll
    for (int j = 0; j < 8; ++j) tmp[j] = arow[j];
    f16x8 af;
    af[0] = (_Float16)tmp[0];
    af[1] = (kg == 3) ? (_Float16)1.0f : (_Float16)tmp[1];
#pragma unroll
    for (int j = 2; j < 8; ++j)
        af[j] = (kg == 3) ? (_Float16)0.0f : (_Float16)tmp[j];

    float s1 = 0.0f, s2 = 0.0f;
#pragma unroll
    for (int n = 0; n < 9; ++n) {
        f32x4 acc = {0.f, 0.f, 0.f, 0.f};
        acc = __builtin_amdgcn_mfma_f32_16x16x32_f16(bfrag[n], af, acc, 0, 0, 0);
        float e0 = __builtin_amdgcn_exp2f(acc[0]);
        float e1 = __builtin_amdgcn_exp2f(acc[1]);
        float e2 = __builtin_amdgcn_exp2f(acc[2]);
        float e3 = __builtin_amdgcn_exp2f(acc[3]);
        if (n < 4) {
            s1 += (e0 + e1) + (e2 + e3);                 // cols 0..63
        } else if (n == 4) {                             // col 64 (kg0,r0) -> S1
            float h = (e0 + e1) + (e2 + e3);
            bool c = (kg == 0);
            s1 += c ? e0 : 0.0f;
            s2 += c ? (h - e0) : h;
        } else {
            s2 += (e0 + e1) + (e2 + e3);                 // cols 80..143 (pads->0)
        }
    }

    s1 += __shfl_xor(s1, 16);
    s1 += __shfl_xor(s1, 32);
    s2 += __shfl_xor(s2, 16);
    s2 += __shfl_xor(s2, 32);

    const float d = 0.34657359027997264f *
                    (__builtin_amdgcn_logf(s1) - __builtin_amdgcn_logf(s2));

    if (kg == 0) dbuf[gw * 16 + r0] = d;                 // 64B/wave, coalesced
}

// ---------------------------------------------------------------------------
// k2: out = w .* mc + d * e0. Pure grid-stride float4 stream; mc is
// L3-resident from k1, d (2MB) is L2/L3-resident. Write-dominated.
// ---------------------------------------------------------------------------
__global__ __launch_bounds__(256)
void mcpf_apply(const float* __restrict__ mc, const float* __restrict__ dbuf,
                float* __restrict__ out, int nf4) {
    const float4* __restrict__ src4 = reinterpret_cast<const float4*>(mc);
    float4* __restrict__ dst4 = reinterpret_cast<float4*>(out);
    const int stride = gridDim.x * 256;
    for (int idx = blockIdx.x * 256 + threadIdx.x; idx < nf4; idx += stride) {
        float4 v = src4[idx];
        int f = idx * 4;
        int q = f / 25;                                  // row
        int r = f - 25 * q;
        float dv0 = dbuf[q];
        float dv1 = dbuf[q + 1];     // 4B past end at q=524287 (r=21): lands
                                     // in ws scratch, value unused (r!=22..24)
        // w per component: 1 for cepstral index 0,1 else 1.2
        v.x *= (r     < 2)                  ? 1.0f : 1.2f;
        v.y *= (r + 1 < 2 || r + 1 == 25)   ? 1.0f : 1.2f;
        v.z *= (r + 2 == 25 || r + 2 == 26) ? 1.0f : 1.2f;
        v.w *= (r + 3 == 25 || r + 3 == 26) ? 1.0f : 1.2f;
        // +d on cepstral index 0 (w=1 there)
        if (r == 0)  v.x += dv0;
        if (r == 22) v.w += dv1;
        if (r == 23) v.z += dv1;
        if (r == 24) v.y += dv1;
        dst4[idx] = v;
    }
}

extern "C" void kernel_launch(void* const* d_in, const int* in_sizes, int n_in,
                              void* d_out, int out_size, void* d_ws, size_t ws_size,
                              hipStream_t stream) {
    const float* mc = (const float*)d_in[0];
    float* out = (float*)d_out;
    float* dbuf = (float*)d_ws;                    // 2 MB of the scratch
    const int rows = in_sizes[0] / 25;             // 524288
    const int nf4  = in_sizes[0] / 4;              // 3,276,800 float4
    mcpf_d<<<dim3(rows / 64), dim3(256), 0, stream>>>(mc, dbuf);       // 8192
    mcpf_apply<<<dim3(2048), dim3(256), 0, stream>>>(mc, dbuf, out, nf4);
}

// Round 17
// 24.269 us; speedup vs baseline: 1.5282x; 1.5282x over previous
//
#include <hip/hip_runtime.h>

// ---------------------------------------------------------------------------
// out = w .* mc + d * e0,   d = 0.5*ln(S1/S2) = 0.5*ln2*(log2 S1 - log2 S2)
// Swapped MFMA (16x16x32 f16):  D = Bmat^T * mc^T; lane's C/D regs hold 4
// spectral cols of ONE mc-row -> reduce = in-lane adds + 2 shfl_xor, after
// which ALL lanes hold S1,S2 (hence d) for their row.
// (b2mc∘mc2b == I so the 25x25 matmuls collapse; verified rounds 1-16.)
//
// R17 = R11 verbatim (best: 24.29us). Per-wave 2-phase software pipeline,
// 4 tiles x 32 rows, double-buffered LDS, counted vmcnt, no block barriers.
// R16's split-kernel experiment (37us) falsified the stream-mixing theory;
// R11 stands as the converged optimum across 7 structural axes (R8/R10/R11/
// R12/R13/R14/R15/R16: 24.5/24.7/24.3/31.8/27.8/24.3/24.4/37.1).
// ---------------------------------------------------------------------------

namespace cg {

constexpr int L  = 128;
constexpr int M1 = 25;

struct CosTab { double v[L]; };
constexpr CosTab make_costab() {
    CosTab t{};
    const double PI = 3.14159265358979323846;
    for (int i = 0; i < L; ++i) {
        int j = (i <= 64) ? i : i - 128;
        double x = (2.0 * PI * (double)j) / 128.0;
        double x2 = x * x, term = 1.0, s = 1.0;
        for (int n = 1; n <= 16; ++n) {
            term *= -x2 / ((2.0 * n - 1.0) * (2.0 * n));
            s += term;
        }
        t.v[i] = s;
    }
    return t;
}
constexpr CosTab CT = make_costab();

struct AMat { double v[L][M1]; };
constexpr AMat make_aft() {
    AMat A{};
    const double al = -0.42;          // freqt called with -ALPHA
    double p = 1.0;
    for (int j = 0; j < M1; ++j) { A.v[0][j] = p; p *= al; }
    double q = 1.0;
    for (int j = 1; j < M1; ++j) { A.v[1][j] = q * (double)j * (1.0 - al * al); q *= al; }
    for (int i = 2; i < L; ++i)
        for (int j = 1; j < M1; ++j)
            A.v[i][j] = A.v[i - 1][j - 1] + al * (A.v[i][j - 1] - A.v[i - 1][j]);
    return A;
}
constexpr AMat AFT = make_aft();

struct Chunk { double v[8][M1]; };
template <int K0>
constexpr Chunk make_chunk() {
    Chunk c{};
    for (int kk = 0; kk < 8; ++kk) {
        int k = K0 + kk;
        for (int m = 0; m < M1; ++m) {
            double s = 0.0;
            for (int l = 0; l < L; ++l)
                s += AFT.v[l][m] * CT.v[(k * l) & 127];
            c.v[kk][m] = s;
        }
    }
    return c;
}
constexpr Chunk CH0 = make_chunk<0>();
constexpr Chunk CH1 = make_chunk<8>();
constexpr Chunk CH2 = make_chunk<16>();
constexpr Chunk CH3 = make_chunk<24>();
constexpr Chunk CH4 = make_chunk<32>();
constexpr Chunk CH5 = make_chunk<40>();
constexpr Chunk CH6 = make_chunk<48>();
constexpr Chunk CH7 = make_chunk<56>();
constexpr Chunk CH8 = make_chunk<64>();

constexpr double chunkval(int bin, int m) {
    const Chunk* chs[9] = { &CH0, &CH1, &CH2, &CH3, &CH4, &CH5, &CH6, &CH7, &CH8 };
    return chs[bin >> 3]->v[bin & 7][m];
}

constexpr double blogical(int k, int col) {
    const double LOG2E = 1.44269504088896340736;
    if (col >= 130) return (k == 25) ? -1.0e4 : 0.0;     // pad cols: exp2 -> 0
    int bin = (col < 65) ? col : (col - 65);
    if (k == 25) return (bin == 0 || bin == 64) ? 0.0 : 1.0;  // log2(bin wt)
    if (k > 25) return 0.0;
    double c = LOG2E * 2.0 * chunkval(bin, k);
    if (col >= 65 && k >= 2) c *= 1.2;                   // cepstral weight
    return c;
}

// constexpr float->half (RN-ish; accuracy far beyond what we need)
constexpr unsigned short f2h(double v) {
    if (v == 0.0) return 0;
    unsigned short s = 0;
    if (v < 0) { s = 0x8000; v = -v; }
    int e = 0;
    while (v >= 2.0) { v *= 0.5; ++e; }
    while (v < 1.0)  { v *= 2.0; --e; }
    if (e > 15) return (unsigned short)(s | 0x7c00);
    if (e < -14) return s;                               // flush tiny to 0
    int mant = (int)((v - 1.0) * 1024.0 + 0.5);
    if (mant == 1024) { mant = 0; ++e; if (e > 15) return (unsigned short)(s | 0x7c00); }
    return (unsigned short)(s | ((e + 15) << 10) | mant);
}

// A-operand fragment per tile: lane l, reg j holds A[i=l&15][k=(l>>4)*8+j]
//   = Bmat[(l>>4)*8+j][N*16 + (l&15)]
struct Tile { unsigned short v[64][8]; };
template <int N>
constexpr Tile make_tile() {
    Tile t{};
    for (int l = 0; l < 64; ++l)
        for (int j = 0; j < 8; ++j)
            t.v[l][j] = f2h(blogical((l >> 4) * 8 + j, N * 16 + (l & 15)));
    return t;
}
constexpr Tile T0 = make_tile<0>();
constexpr Tile T1 = make_tile<1>();
constexpr Tile T2 = make_tile<2>();
constexpr Tile T3 = make_tile<3>();
constexpr Tile T4 = make_tile<4>();
constexpr Tile T5 = make_tile<5>();
constexpr Tile T6 = make_tile<6>();
constexpr Tile T7 = make_tile<7>();
constexpr Tile T8 = make_tile<8>();

struct BH { alignas(16) unsigned short v[9][64][8]; };
constexpr BH make_bh() {
    BH b{};
    const Tile* ts[9] = { &T0, &T1, &T2, &T3, &T4, &T5, &T6, &T7, &T8 };
    for (int n = 0; n < 9; ++n)
        for (int l = 0; l < 64; ++l)
            for (int j = 0; j < 8; ++j)
                b.v[n][l][j] = ts[n]->v[l][j];
    return b;
}

} // namespace cg

__device__ const cg::BH g_Bh = cg::make_bh();

typedef _Float16 f16x8 __attribute__((ext_vector_type(8)));
typedef float    f32x4 __attribute__((ext_vector_type(4)));

// ---------------------------------------------------------------------------
// 256 threads = 4 independent waves; each wave owns 4 tiles x 32 rows with
// double-buffered LDS (2 x 800 floats). No block barriers, counted vmcnt.
// ---------------------------------------------------------------------------
__global__ __launch_bounds__(256, 4)
void mcpf_kernel(const float* __restrict__ mc, float* __restrict__ out) {
    __shared__ __align__(16) float sbuf[4 * 1600 + 8];   // 25.6 KB (+overread pad)
    const int tid  = threadIdx.x;
    const int lane = tid & 63;
    const int wv   = tid >> 6;
    const int r0   = lane & 15;     // mc-row within 16-group
    const int kg   = lane >> 4;     // K group 0..3 (col group / k-slice)

    float* __restrict__ wbase = &sbuf[wv * 1600];        // this wave's 2 buffers
    const long long gw = (long long)blockIdx.x * 4 + wv; // global wave id
    const long long t0f4 = gw * 800;                     // float4 idx of tile 0

    const float4* __restrict__ src4  = reinterpret_cast<const float4*>(mc);
    float4*       __restrict__ dst4g = reinterpret_cast<float4*>(out);

    // B-matrix fragments (rodata, L2-resident): 9x 16B loads
    f16x8 bfrag[9];
#pragma unroll
    for (int n = 0; n < 9; ++n)
        bfrag[n] = *reinterpret_cast<const f16x8*>(&g_Bh.v[n][lane][0]);

    // stage tile t into buffer b: 200 float4, 4 global_load_lds instrs
#define STAGE(b, t)                                                          \
    do {                                                                     \
        const float4* __restrict__ s_ = src4 + t0f4 + (t) * 200;             \
        float* db_ = wbase + (b) * 800;                                      \
        _Pragma("unroll")                                                    \
        for (int j_ = 0; j_ < 3; ++j_)                                       \
            __builtin_amdgcn_global_load_lds(                                \
                (const __attribute__((address_space(1))) float*)             \
                    (const float*)(s_ + lane + j_ * 64),                     \
                (__attribute__((address_space(3))) float*)(db_ + j_ * 256),  \
                16, 0, 0);                                                   \
        if (lane < 8)                                                        \
            __builtin_amdgcn_global_load_lds(                                \
                (const __attribute__((address_space(1))) float*)             \
                    (const float*)(s_ + lane + 192),                         \
                (__attribute__((address_space(3))) float*)(db_ + 768),       \
                16, 0, 0);                                                   \
    } while (0)

    STAGE(0, 0);                                         // prologue

#pragma unroll
    for (int t = 0; t < 4; ++t) {
        if (t < 3) STAGE((t + 1) & 1, t + 1);            // prefetch next tile

        // wait for tile t's 4 loads: outstanding after them is
        // [stores(t-1) 4][loads(t+1) 4] mid-loop, [loads(t+1) 4] at t=0,
        // [stores(t-1) 4] at t=3.
        if (t == 0 || t == 3) asm volatile("s_waitcnt vmcnt(4)" ::: "memory");
        else                  asm volatile("s_waitcnt vmcnt(8)" ::: "memory");

        float* __restrict__ cbuf = wbase + (t & 1) * 800;
        float4* __restrict__ cb4 = reinterpret_cast<float4*>(cbuf);
        float4* __restrict__ dt4 = dst4g + t0f4 + t * 200;

#pragma unroll
        for (int g = 0; g < 2; ++g) {
            const float* __restrict__ arow = &cbuf[(g * 16 + r0) * 25 + kg * 8];

            // data fragment (B-operand): lane holds row r0, k = kg*8 + j.
            // kg==3 overreads into next row/pad, fixed up branchlessly.
            float tmp[8];
#pragma unroll
            for (int j = 0; j < 8; ++j) tmp[j] = arow[j];
            f16x8 af;
            af[0] = (_Float16)tmp[0];
            af[1] = (kg == 3) ? (_Float16)1.0f : (_Float16)tmp[1];
#pragma unroll
            for (int j = 2; j < 8; ++j)
                af[j] = (kg == 3) ? (_Float16)0.0f : (_Float16)tmp[j];

            // D[col][row]: this lane gets row r0, cols n*16 + kg*4 + r
            float s1 = 0.0f, s2 = 0.0f;
#pragma unroll
            for (int n = 0; n < 9; ++n) {
                f32x4 acc = {0.f, 0.f, 0.f, 0.f};
                acc = __builtin_amdgcn_mfma_f32_16x16x32_f16(bfrag[n], af, acc, 0, 0, 0);
                float e0 = __builtin_amdgcn_exp2f(acc[0]);
                float e1 = __builtin_amdgcn_exp2f(acc[1]);
                float e2 = __builtin_amdgcn_exp2f(acc[2]);
                float e3 = __builtin_amdgcn_exp2f(acc[3]);
                if (n < 4) {
                    s1 += (e0 + e1) + (e2 + e3);         // cols 0..63
                } else if (n == 4) {                     // col 64 (kg0,r0) -> S1
                    float h = (e0 + e1) + (e2 + e3);
                    bool c = (kg == 0);
                    s1 += c ? e0 : 0.0f;
                    s2 += c ? (h - e0) : h;
                } else {
                    s2 += (e0 + e1) + (e2 + e3);         // cols 80..143 (pads->0)
                }
            }

            // butterfly over lane bits 4,5 -> ALL lanes get totals
            s1 += __shfl_xor(s1, 16);
            s1 += __shfl_xor(s1, 32);
            s2 += __shfl_xor(s2, 16);
            s2 += __shfl_xor(s2, 32);

            // every lane: d for its row (tile row g*16 + r0)
            const float d = 0.34657359027997264f *
                            (__builtin_amdgcn_logf(s1) - __builtin_amdgcn_logf(s2));

            // store this group's 16 rows = exactly 100 float4 (group-aligned);
            // d via shfl from lane (q or q+1)&15 (always lane<16 = active).
#pragma unroll
            for (int j = 0; j < 2; ++j) {
                int t2 = lane + j * 64;
                if (t2 < 100) {
                    int idx = g * 100 + t2;              // tile-local float4 idx
                    float4 v = cb4[idx];
                    int f = idx * 4;
                    int q = f / 25;                      // tile-local row
                    int r = f - 25 * q;
                    int srcl = ((r == 0) ? q : q + 1) & 15;
                    float dv = __shfl(d, srcl);
                    // w per component: 1 for cepstral index 0,1 else 1.2
                    v.x *= (r     < 2)                  ? 1.0f : 1.2f;
                    v.y *= (r + 1 < 2 || r + 1 == 25)   ? 1.0f : 1.2f;
                    v.z *= (r + 2 == 25 || r + 2 == 26) ? 1.0f : 1.2f;
                    v.w *= (r + 3 == 25 || r + 3 == 26) ? 1.0f : 1.2f;
                    // +d on cepstral index 0 (w=1 there)
                    if (r == 0)  v.x += dv;
                    if (r == 22) v.w += dv;
                    if (r == 23) v.z += dv;
                    if (r == 24) v.y += dv;
                    dt4[idx] = v;
                }
            }
        }
    }
#undef STAGE
}

extern "C" void kernel_launch(void* const* d_in, const int* in_sizes, int n_in,
                              void* d_out, int out_size, void* d_ws, size_t ws_size,
                              hipStream_t stream) {
    const float* mc = (const float*)d_in[0];
    float* out = (float*)d_out;
    const int rows = in_sizes[0] / 25;             // 524288
    const int blocks = rows / 512;                 // 1024 (4 waves x 128 rows)
    mcpf_kernel<<<dim3(blocks), dim3(256), 0, stream>>>(mc, out);
}